// Round 13
// baseline (83.302 us; speedup 1.0000x reference)
//
#include <hip/hip_runtime.h>
#include <hip/hip_bf16.h>
#include <stdint.h>

typedef _Float16 f16x8 __attribute__((ext_vector_type(8)));
typedef float    f32x4 __attribute__((ext_vector_type(4)));

#define CIN   64
#define COUT  128
#define HH    128
#define WW    128
#define BB    8

#define TROW  130                         // y' rows per batch (halo rows 0,129 zero)
#define ROWBYTES (130 * 128)              // 16640 B per (b,y') row: 130 x' * 64c * 2B
#define TSIZE ((size_t)BB * TROW * ROWBYTES)   // 17,305,600 B

// T row byte layout (f16, c-innermost, PLAIN — no swizzle; reads are from L2):
//   byte(x', c) = x'*128 + c*2

// ---------------- pass 0: weights -> MFMA-A frag order (f16) + halo-row zeroing --
// frag[((ot*18 + s)*64 + lane)*8 + j] = W2[ot*16+(l&15)][c*9+k],
//   c = (s&1)*32 + ((l>>4)&3)*8 + j; k = s>>1
__global__ void prep_plus(const float* __restrict__ wflat, _Float16* __restrict__ bp,
                          _Float16* __restrict__ T) {
    int gid = blockIdx.x * 256 + threadIdx.x;
    if (gid < 8 * 18 * 64 * 8) {
        int j = gid & 7;
        int l = (gid >> 3) & 63;
        int s = (gid >> 9) % 18;
        int n = gid / (18 * 512);
        int o = n * 16 + (l & 15);
        int c = ((s & 1) << 5) + ((l >> 4) << 3) + j;
        int k = s >> 1;
        bp[gid] = (_Float16)wflat[o * 576 + c * 9 + k];
        return;
    }
    int h = gid - 8 * 18 * 64 * 8;
    if (h < 16 * 1040) {                  // zero halo rows y'=0,129 of each batch
        int row = h / 1040, c = h - row * 1040;
        int b = row >> 1, yp = (row & 1) * 129;
        f16x8 z = {};
        *(f16x8*)((char*)T + (size_t)(b * TROW + yp) * ROWBYTES + c * 16) = z;
    }
}

// ---------------- pass 1: input (B,C,H,W) f32 -> T[b][y'][x'][c] f16, plain ------
__global__ __launch_bounds__(256) void transpose_pass(const float* __restrict__ inp,
                                                      _Float16* __restrict__ T) {
    __shared__ float sT[64][129];
    const int b   = blockIdx.x >> 7;
    const int y   = blockIdx.x & 127;
    const int tid = threadIdx.x;

    const float* ib = inp + ((long)b * CIN * HH + y) * WW;
    const int xq = tid & 31, c8 = tid >> 5;
    #pragma unroll
    for (int i = 0; i < 8; ++i) {
        int c = c8 * 8 + i;
        float4 v = *(const float4*)(ib + (long)c * (HH * WW) + (xq << 2));
        *(float4*)&sT[c][xq << 2] = v;
    }
    __syncthreads();

    const int x  = tid & 127;
    const int ch = tid >> 7;
    char* rowp = (char*)T + (size_t)(b * TROW + y + 1) * ROWBYTES + (size_t)(x + 1) * 128;
    for (int c0 = ch * 8; c0 < 64; c0 += 16) {
        f16x8 v;
        #pragma unroll
        for (int j = 0; j < 8; ++j) v[j] = (_Float16)sT[c0 + j][x];
        *(f16x8*)(rowp + c0 * 2) = v;
    }
    if (tid < 16) {   // zero col halos x'=0, x'=129
        char* basep = (char*)T + (size_t)(b * TROW + y + 1) * ROWBYTES
                    + ((tid >> 3) ? 129 * 128 : 0) + (tid & 7) * 16;
        f16x8 z = {};
        *(f16x8*)basep = z;
    }
}

// ---- pass 2: main — block = (b, 2-row strip, 32-px quarter), all 128 o ----------
// 256 thr = 4 waves (oi 0..3): each 2 o-tiles x 2 px-tiles x 2 rows.
// NO input LDS staging: T slices are L2-resident, read directly from global with
// perfectly-coalesced base+imm loads. Only wf lives in LDS (1.3 KB). One barrier;
// the whole K-loop is barrier-free global->MFMA dataflow the compiler can pipeline.
__global__ __launch_bounds__(256, 4) void depthcnn_main(
    const _Float16* __restrict__ T, const float* __restrict__ gbuf,
    const float* __restrict__ bias, const _Float16* __restrict__ aprep,
    float* __restrict__ out)
{
    __shared__ _Float16 sWf[2][9][36];                   // 1,296 B total LDS

    const int blk    = blockIdx.x;
    const int b      = blk & 7;            // XCD-pinned: batch b -> XCD b
    const int rest   = blk >> 3;
    const int strip  = rest & 63;          // 2-row strip
    const int xq     = rest >> 6;          // 32-px quarter (0..3)
    const int ystart = strip << 1;
    const int x0     = xq << 5;

    const int tid  = threadIdx.x;
    const int wave = tid >> 6;             // oi 0..3
    const int lane = tid & 63;
    const int oi   = wave;
    const int l15  = lane & 15;
    const int g4   = lane >> 4;

    // ---- per-trow lane base pointers: btr[tr] + imm(pt*2048 + dx*128 + ch*64)
    const char* Tb = (const char*)T + ((size_t)b * TROW + ystart) * ROWBYTES
                   + (size_t)x0 * 128 + (l15 << 7) + (g4 << 4);
    const char* btr[4];
    #pragma unroll
    for (int tr = 0; tr < 4; ++tr) btr[tr] = Tb + tr * ROWBYTES;

    // ---- weight base pointers + tap-0 frags issued before the barrier
    const f16x8* __restrict__ ap = (const f16x8*)aprep;
    const char* wp0 = (const char*)ap + (size_t)((oi * 2 + 0) * 18) * 1024 + lane * 16;
    const char* wp1 = (const char*)ap + (size_t)((oi * 2 + 1) * 18) * 1024 + lane * 16;
    f16x8 af[2][2][2];                     // [parity][t2][ch]
    af[0][0][0] = *(const f16x8*)(wp0);
    af[0][0][1] = *(const f16x8*)(wp0 + 1024);
    af[0][1][0] = *(const f16x8*)(wp1);
    af[0][1][1] = *(const f16x8*)(wp1 + 1024);

    // ---- wf for 2 rows x 32 px
    if (tid < 64) {
        const int r = tid >> 5, pxl = tid & 31, x = x0 + pxl, y = ystart + r;
        const float* g = gbuf + ((size_t)b * 2 + 1) * (HH * WW);
        float dc = 2.f * (g[y * WW + x] - 0.5f);
        float e[9];
        float ssum = 0.f;
        #pragma unroll
        for (int k = 0; k < 9; ++k) {
            int yy = y + (k / 3) - 1;
            int xx = x + (k % 3) - 1;
            float dn = 0.f;
            if ((unsigned)yy < 128u && (unsigned)xx < 128u)
                dn = 2.f * (g[yy * WW + xx] - 0.5f);
            float df = dn - dc;
            float ek = __expf(-df * df);
            e[k] = ek;
            ssum += ek;
        }
        float sc = 9.f / ssum;
        #pragma unroll
        for (int k = 0; k < 9; ++k) sWf[r][k][pxl] = (_Float16)(e[k] * sc);
    }

    __syncthreads();   // ONE barrier: wf visible. K-loop below is barrier-free.

    const char* bwf = (const char*)&sWf[0][0][0] + l15 * 2;   // + (r*9+k)*72 + pt*32

    f32x4 acc[2][2][2];   // [row][t2][pt]
    #pragma unroll
    for (int r = 0; r < 2; ++r)
        #pragma unroll
        for (int t2 = 0; t2 < 2; ++t2)
            #pragma unroll
            for (int pt = 0; pt < 2; ++pt)
                acc[r][t2][pt] = (f32x4){0.f, 0.f, 0.f, 0.f};

    #pragma unroll
    for (int k = 0; k < 9; ++k) {
        if (k < 8) {   // prefetch tap k+1 weight frags into alternate buffer
            const char* q0 = wp0 + (k + 1) * 2048;
            const char* q1 = wp1 + (k + 1) * 2048;
            af[(k + 1) & 1][0][0] = *(const f16x8*)(q0);
            af[(k + 1) & 1][0][1] = *(const f16x8*)(q0 + 1024);
            af[(k + 1) & 1][1][0] = *(const f16x8*)(q1);
            af[(k + 1) & 1][1][1] = *(const f16x8*)(q1 + 1024);
        }
        const int dy = k / 3;
        const int dx = k - 3 * dy;
        #pragma unroll
        for (int r = 0; r < 2; ++r) {
            _Float16 wh[2];
            #pragma unroll
            for (int pt = 0; pt < 2; ++pt)
                wh[pt] = *(const _Float16*)(bwf + ((r * 9 + k) * 72 + pt * 32));
            #pragma unroll
            for (int ch = 0; ch < 2; ++ch) {
                f16x8 bf[2];
                #pragma unroll
                for (int pt = 0; pt < 2; ++pt) {
                    // coalesced L2 read: 16 full 64B lines per instruction
                    f16x8 iv = *(const f16x8*)(btr[r + dy]
                             + ((pt << 11) + dx * 128 + ch * 64));
                    f16x8 w8 = {wh[pt], wh[pt], wh[pt], wh[pt],
                                wh[pt], wh[pt], wh[pt], wh[pt]};
                    bf[pt] = iv * w8;
                }
                #pragma unroll
                for (int t2 = 0; t2 < 2; ++t2)
                    #pragma unroll
                    for (int pt = 0; pt < 2; ++pt)
                        acc[r][t2][pt] = __builtin_amdgcn_mfma_f32_16x16x32_f16(
                            af[k & 1][t2][ch], bf[pt], acc[r][t2][pt], 0, 0, 0);
            }
        }
    }

    // ---- epilogue: D row = o (g4*4+r4), col = px (l15) -> full 64B lines
    float* ob = out + (size_t)b * COUT * (HH * WW) + x0;
    #pragma unroll
    for (int r = 0; r < 2; ++r) {
        const int y = ystart + r;
        #pragma unroll
        for (int t2 = 0; t2 < 2; ++t2) {
            #pragma unroll
            for (int pt = 0; pt < 2; ++pt) {
                #pragma unroll
                for (int r4 = 0; r4 < 4; ++r4) {
                    const int o = (oi << 5) + (t2 << 4) + (g4 << 2) + r4;
                    ob[(size_t)o * (HH * WW) + (size_t)y * WW + (pt << 4) + l15]
                        = acc[r][t2][pt][r4] + bias[o];
                }
            }
        }
    }
}

extern "C" void kernel_launch(void* const* d_in, const int* in_sizes, int n_in,
                              void* d_out, int out_size, void* d_ws, size_t ws_size,
                              hipStream_t stream) {
    const float* inp  = (const float*)d_in[0];
    const float* gbuf = (const float*)d_in[1];
    const float* wts  = (const float*)d_in[2];
    const float* bias = (const float*)d_in[3];

    _Float16* T  = (_Float16*)d_ws;                     // 17,305,600 B
    _Float16* bp = (_Float16*)((char*)d_ws + TSIZE);    // +147,456 B

    hipLaunchKernelGGL(prep_plus, dim3(353), dim3(256), 0, stream, wts, bp, T);
    hipLaunchKernelGGL(transpose_pass, dim3(BB * HH), dim3(256), 0, stream, inp, T);
    hipLaunchKernelGGL(depthcnn_main, dim3(2048), dim3(256), 0, stream,
                       T, gbuf, bias, bp, (float*)d_out);
}

// Round 14
// 50.209 us; speedup vs baseline: 1.6591x; 1.6591x over previous
//
#include <hip/hip_runtime.h>
#include <hip/hip_bf16.h>
#include <stdint.h>

typedef _Float16 f16x8 __attribute__((ext_vector_type(8)));
typedef float    f32x4 __attribute__((ext_vector_type(4)));

#define CIN   64
#define COUT  128
#define HH    128
#define WW    128
#define BB    8

#define TROW  130                         // y' rows per batch (halo rows 0,129 zero)
#define ROWBYTES (130 * 128)              // 16640 B per (b,y') row: 130 x' * 64c * 2B
#define TSIZE ((size_t)BB * TROW * ROWBYTES)   // 17,305,600 B

#define LROWB (34 * 128)                  // 4352 B: staged 34-col slice of one trow
#define NCHKT (4 * 272)                   // total 16B chunks staged (4 trows x 272)

#define AS1 __attribute__((address_space(1)))
#define AS3 __attribute__((address_space(3)))

// T row byte layout (f16, c-innermost, XOR-swizzled 16B slots):
//   byte(x', c) = x'*128 + (((c>>3) ^ (x'&7)) << 4) + (c&7)*2

// ---------------- pass 0: weights -> MFMA-A frag order (f16) + halo-row zeroing --
// frag[((ot*18 + s)*64 + lane)*8 + j] = W2[ot*16+(l&15)][c*9+k],
//   c = (s&1)*32 + ((l>>4)&3)*8 + j; k = s>>1
__global__ void prep_plus(const float* __restrict__ wflat, _Float16* __restrict__ bp,
                          _Float16* __restrict__ T) {
    int gid = blockIdx.x * 256 + threadIdx.x;
    if (gid < 8 * 18 * 64 * 8) {
        int j = gid & 7;
        int l = (gid >> 3) & 63;
        int s = (gid >> 9) % 18;
        int n = gid / (18 * 512);
        int o = n * 16 + (l & 15);
        int c = ((s & 1) << 5) + ((l >> 4) << 3) + j;
        int k = s >> 1;
        bp[gid] = (_Float16)wflat[o * 576 + c * 9 + k];
        return;
    }
    int h = gid - 8 * 18 * 64 * 8;
    if (h < 16 * 1040) {                  // zero halo rows y'=0,129 of each batch
        int row = h / 1040, c = h - row * 1040;
        int b = row >> 1, yp = (row & 1) * 129;
        f16x8 z = {};
        *(f16x8*)((char*)T + (size_t)(b * TROW + yp) * ROWBYTES + c * 16) = z;
    }
}

// ---------------- pass 1: input (B,C,H,W) f32 -> T[b][y'][x'][c] f16, swizzled ---
__global__ __launch_bounds__(256) void transpose_pass(const float* __restrict__ inp,
                                                      _Float16* __restrict__ T) {
    __shared__ float sT[64][129];
    const int b   = blockIdx.x >> 7;
    const int y   = blockIdx.x & 127;
    const int tid = threadIdx.x;

    const float* ib = inp + ((long)b * CIN * HH + y) * WW;
    const int xq = tid & 31, c8 = tid >> 5;
    #pragma unroll
    for (int i = 0; i < 8; ++i) {
        int c = c8 * 8 + i;
        float4 v = *(const float4*)(ib + (long)c * (HH * WW) + (xq << 2));
        *(float4*)&sT[c][xq << 2] = v;
    }
    __syncthreads();

    const int x  = tid & 127;
    const int ch = tid >> 7;
    char* rowp = (char*)T + (size_t)(b * TROW + y + 1) * ROWBYTES + (size_t)(x + 1) * 128;
    const int sw = (x + 1) & 7;
    for (int c0 = ch * 8; c0 < 64; c0 += 16) {
        f16x8 v;
        #pragma unroll
        for (int j = 0; j < 8; ++j) v[j] = (_Float16)sT[c0 + j][x];
        *(f16x8*)(rowp + (((c0 >> 3) ^ sw) << 4)) = v;
    }
    if (tid < 16) {   // zero col halos x'=0, x'=129
        char* basep = (char*)T + (size_t)(b * TROW + y + 1) * ROWBYTES
                    + ((tid >> 3) ? 129 * 128 : 0) + (tid & 7) * 16;
        f16x8 z = {};
        *(f16x8*)basep = z;
    }
}

// ---- pass 2: main — block = (b, 2-row strip, 32-px quarter), all 128 o ----------
// 256 thr = 4 waves (oi 0..3). DE-CONVOYED: wave w iterates taps in rotated order
// (i + 2w) mod 9 (acc is order-independent), so concurrent waves occupy DIFFERENT
// pipes (LDS / VALU / MFMA / weight-L2) at any instant. wf spread across all
// waves; setprio(1) around MFMA clusters arbitrates in favor of tensor pipe.
__global__ __launch_bounds__(256, 4) void depthcnn_main(
    const _Float16* __restrict__ T, const float* __restrict__ gbuf,
    const float* __restrict__ bias, const _Float16* __restrict__ aprep,
    float* __restrict__ out)
{
    __shared__ __align__(1024) char sIn[4 * LROWB];      // 17,408 B: 4 trow slices
    __shared__ _Float16 sWf[2][9][36];                   // 1,296 B -> 18,704 total

    const int blk    = blockIdx.x;
    const int b      = blk & 7;            // XCD-pinned: batch b -> XCD b
    const int rest   = blk >> 3;
    const int strip  = rest & 63;          // 2-row strip
    const int xq     = rest >> 6;          // 32-px quarter (0..3)
    const int ystart = strip << 1;
    const int x0     = xq << 5;

    const int tid  = threadIdx.x;
    const int wave = tid >> 6;             // oi 0..3
    const int lane = tid & 63;
    const int oi   = wave;
    const int l15  = lane & 15;
    const int g4   = lane >> 4;
    const int off  = wave << 1;            // tap rotation: 0,2,4,6

    // ---- stage 4 trow slices (ystart..ystart+3) x 34 cols via async DMA
    {
        const char* Tb = (const char*)T + ((size_t)b * TROW + ystart) * ROWBYTES
                       + (size_t)x0 * 128;
        #pragma unroll
        for (int tt = 0; tt < 5; ++tt) {
            int t = tt * 256 + tid;
            if (t < NCHKT) {
                int tr = t / 272, c = t - tr * 272;
                __builtin_amdgcn_global_load_lds(
                    (const AS1 uint32_t*)(Tb + (size_t)tr * ROWBYTES + c * 16),
                    (AS3 uint32_t*)(sIn + tr * LROWB + c * 16), 16, 0, 0);
            }
        }
    }

    // ---- weight base pointers + THIS WAVE'S starting-tap frags (staggered L2 hits)
    const f16x8* __restrict__ ap = (const f16x8*)aprep;
    const char* wp0 = (const char*)ap + (size_t)((oi * 2 + 0) * 18) * 1024 + lane * 16;
    const char* wp1 = (const char*)ap + (size_t)((oi * 2 + 1) * 18) * 1024 + lane * 16;
    f16x8 af[2][2][2];                     // [parity][t2][ch]
    {
        const char* q0 = wp0 + (off << 11);
        const char* q1 = wp1 + (off << 11);
        af[0][0][0] = *(const f16x8*)(q0);
        af[0][0][1] = *(const f16x8*)(q0 + 1024);
        af[0][1][0] = *(const f16x8*)(q1);
        af[0][1][1] = *(const f16x8*)(q1 + 1024);
    }

    // ---- wf for 2 rows x 32 px — SPREAD: 16 lanes of EVERY wave (no serial wave0)
    if (g4 == 0) {
        const int item = (wave << 4) | l15;   // 0..63
        const int r = item >> 5, pxl = item & 31, x = x0 + pxl, y = ystart + r;
        const float* g = gbuf + ((size_t)b * 2 + 1) * (HH * WW);
        float dc = 2.f * (g[y * WW + x] - 0.5f);
        float e[9];
        float ssum = 0.f;
        #pragma unroll
        for (int k = 0; k < 9; ++k) {
            int yy = y + (k / 3) - 1;
            int xx = x + (k % 3) - 1;
            float dn = 0.f;
            if ((unsigned)yy < 128u && (unsigned)xx < 128u)
                dn = 2.f * (g[yy * WW + xx] - 0.5f);
            float df = dn - dc;
            float ek = __expf(-df * df);
            e[k] = ek;
            ssum += ek;
        }
        float sc = 9.f / ssum;
        #pragma unroll
        for (int k = 0; k < 9; ++k) sWf[r][k][pxl] = (_Float16)(e[k] * sc);
    }

    __syncthreads();   // ONE barrier: DMA stage + wf writes visible

    const char* bwf = (const char*)&sWf[0][0][0] + l15 * 2;   // + r*648 + k*72 + pt*32

    f32x4 acc[2][2][2];   // [row][t2][pt]
    #pragma unroll
    for (int r = 0; r < 2; ++r)
        #pragma unroll
        for (int t2 = 0; t2 < 2; ++t2)
            #pragma unroll
            for (int pt = 0; pt < 2; ++pt)
                acc[r][t2][pt] = (f32x4){0.f, 0.f, 0.f, 0.f};

    #pragma unroll
    for (int i = 0; i < 9; ++i) {
        int k = i + off; k = (k >= 9) ? k - 9 : k;          // this wave's tap
        if (i < 8) {   // prefetch next rotated tap's weight frags
            int kn = k + 1; kn = (kn >= 9) ? kn - 9 : kn;
            const char* q0 = wp0 + (kn << 11);
            const char* q1 = wp1 + (kn << 11);
            af[(i + 1) & 1][0][0] = *(const f16x8*)(q0);
            af[(i + 1) & 1][0][1] = *(const f16x8*)(q0 + 1024);
            af[(i + 1) & 1][1][0] = *(const f16x8*)(q1);
            af[(i + 1) & 1][1][1] = *(const f16x8*)(q1 + 1024);
        }
        const int dy  = (k * 11) >> 5;        // k/3 for k<10
        const int dx  = k - dy * 3;
        const int xl  = l15 + dx;
        const int s7  = xl & 7;
        const int dyb = dy * LROWB;
        const int kwf = k * 72;
        // swizzled column bases for ch=0,1 (runtime, hoisted per tap)
        const char* cb0 = sIn + ((xl << 7) + ((g4 ^ s7) << 4));
        const char* cb1 = sIn + ((xl << 7) + (((4 | g4) ^ s7) << 4));
        #pragma unroll
        for (int r = 0; r < 2; ++r) {
            _Float16 wh[2];
            #pragma unroll
            for (int pt = 0; pt < 2; ++pt)
                wh[pt] = *(const _Float16*)(bwf + kwf + (r * 648 + pt * 32));
            const int rb = dyb + r * LROWB;
            #pragma unroll
            for (int ch = 0; ch < 2; ++ch) {
                const char* cb = ch ? cb1 : cb0;
                f16x8 bf[2];
                #pragma unroll
                for (int pt = 0; pt < 2; ++pt) {
                    f16x8 iv = *(const f16x8*)(cb + rb + (pt << 11));
                    f16x8 w8 = {wh[pt], wh[pt], wh[pt], wh[pt],
                                wh[pt], wh[pt], wh[pt], wh[pt]};
                    bf[pt] = iv * w8;
                }
                __builtin_amdgcn_s_setprio(1);
                #pragma unroll
                for (int t2 = 0; t2 < 2; ++t2)
                    #pragma unroll
                    for (int pt = 0; pt < 2; ++pt)
                        acc[r][t2][pt] = __builtin_amdgcn_mfma_f32_16x16x32_f16(
                            af[i & 1][t2][ch], bf[pt], acc[r][t2][pt], 0, 0, 0);
                __builtin_amdgcn_s_setprio(0);
            }
        }
    }

    // ---- epilogue: D row = o (g4*4+r4), col = px (l15) -> full 64B lines
    float* ob = out + (size_t)b * COUT * (HH * WW) + x0;
    #pragma unroll
    for (int r = 0; r < 2; ++r) {
        const int y = ystart + r;
        #pragma unroll
        for (int t2 = 0; t2 < 2; ++t2) {
            #pragma unroll
            for (int pt = 0; pt < 2; ++pt) {
                #pragma unroll
                for (int r4 = 0; r4 < 4; ++r4) {
                    const int o = (oi << 5) + (t2 << 4) + (g4 << 2) + r4;
                    ob[(size_t)o * (HH * WW) + (size_t)y * WW + (pt << 4) + l15]
                        = acc[r][t2][pt][r4] + bias[o];
                }
            }
        }
    }
}

extern "C" void kernel_launch(void* const* d_in, const int* in_sizes, int n_in,
                              void* d_out, int out_size, void* d_ws, size_t ws_size,
                              hipStream_t stream) {
    const float* inp  = (const float*)d_in[0];
    const float* gbuf = (const float*)d_in[1];
    const float* wts  = (const float*)d_in[2];
    const float* bias = (const float*)d_in[3];

    _Float16* T  = (_Float16*)d_ws;                     // 17,305,600 B
    _Float16* bp = (_Float16*)((char*)d_ws + TSIZE);    // +147,456 B

    hipLaunchKernelGGL(prep_plus, dim3(353), dim3(256), 0, stream, wts, bp, T);
    hipLaunchKernelGGL(transpose_pass, dim3(BB * HH), dim3(256), 0, stream, inp, T);
    hipLaunchKernelGGL(depthcnn_main, dim3(2048), dim3(256), 0, stream,
                       T, gbuf, bias, bp, (float*)d_out);
}

// Round 15
// 47.614 us; speedup vs baseline: 1.7495x; 1.0545x over previous
//
#include <hip/hip_runtime.h>
#include <hip/hip_bf16.h>
#include <stdint.h>

typedef _Float16 f16x8 __attribute__((ext_vector_type(8)));
typedef float    f32x4 __attribute__((ext_vector_type(4)));

#define CIN   64
#define COUT  128
#define HH    128
#define WW    128
#define BB    8

#define TROW  130                         // y' rows per batch (halo rows 0,129 zero)
#define ROWBYTES (130 * 128)              // 16640 B per (b,y') row: 130 x' * 64c * 2B
#define TSIZE ((size_t)BB * TROW * ROWBYTES)   // 17,305,600 B

#define AS1 __attribute__((address_space(1)))
#define AS3 __attribute__((address_space(3)))

// T row byte layout (f16, c-innermost, XOR-swizzled 16B slots):
//   byte(x', c) = x'*128 + (((c>>3) ^ (x'&7)) << 4) + (c&7)*2

// ---------------- pass 0: weights -> MFMA-A frag order (f16) + halo-row zeroing --
// frag[((ot*18 + s)*64 + lane)*8 + j] = W2[ot*16+(l&15)][c*9+k],
//   c = (s&1)*32 + ((l>>4)&3)*8 + j; k = s>>1
__global__ void prep_plus(const float* __restrict__ wflat, _Float16* __restrict__ bp,
                          _Float16* __restrict__ T) {
    int gid = blockIdx.x * 256 + threadIdx.x;
    if (gid < 8 * 18 * 64 * 8) {
        int j = gid & 7;
        int l = (gid >> 3) & 63;
        int s = (gid >> 9) % 18;
        int n = gid / (18 * 512);
        int o = n * 16 + (l & 15);
        int c = ((s & 1) << 5) + ((l >> 4) << 3) + j;
        int k = s >> 1;
        bp[gid] = (_Float16)wflat[o * 576 + c * 9 + k];
        return;
    }
    int h = gid - 8 * 18 * 64 * 8;
    if (h < 16 * 1040) {                  // zero halo rows y'=0,129 of each batch
        int row = h / 1040, c = h - row * 1040;
        int b = row >> 1, yp = (row & 1) * 129;
        f16x8 z = {};
        *(f16x8*)((char*)T + (size_t)(b * TROW + yp) * ROWBYTES + c * 16) = z;
    }
}

// ---------------- pass 1: input (B,C,H,W) f32 -> T[b][y'][x'][c] f16, swizzled ---
__global__ __launch_bounds__(256) void transpose_pass(const float* __restrict__ inp,
                                                      _Float16* __restrict__ T) {
    __shared__ float sT[64][129];
    const int b   = blockIdx.x >> 7;
    const int y   = blockIdx.x & 127;
    const int tid = threadIdx.x;

    const float* ib = inp + ((long)b * CIN * HH + y) * WW;
    const int xq = tid & 31, c8 = tid >> 5;
    #pragma unroll
    for (int i = 0; i < 8; ++i) {
        int c = c8 * 8 + i;
        float4 v = *(const float4*)(ib + (long)c * (HH * WW) + (xq << 2));
        *(float4*)&sT[c][xq << 2] = v;
    }
    __syncthreads();

    const int x  = tid & 127;
    const int ch = tid >> 7;
    char* rowp = (char*)T + (size_t)(b * TROW + y + 1) * ROWBYTES + (size_t)(x + 1) * 128;
    const int sw = (x + 1) & 7;
    for (int c0 = ch * 8; c0 < 64; c0 += 16) {
        f16x8 v;
        #pragma unroll
        for (int j = 0; j < 8; ++j) v[j] = (_Float16)sT[c0 + j][x];
        *(f16x8*)(rowp + (((c0 >> 3) ^ sw) << 4)) = v;
    }
    if (tid < 16) {   // zero col halos x'=0, x'=129
        char* basep = (char*)T + (size_t)(b * TROW + y + 1) * ROWBYTES
                    + ((tid >> 3) ? 129 * 128 : 0) + (tid & 7) * 16;
        f16x8 z = {};
        *(f16x8*)basep = z;
    }
}

// ---- pass 2: main — block = (b, 2-row strip), FULL 128 px x 128 o ---------------
// 256 thr = 4 waves = 4 px-quarters; EACH wave computes ALL 128 o for its 32 px
// x 2 rows. Per K-step: 4 ds_read_b128 -> 32 MFMAs (read:MFMA = 0.125). Weights
// streamed once per wave (147KB, L2-hot) via 2-deep double buffer af[2][8].
// acc[2][2][8] in AGPRs. One barrier; K-loop barrier-free, base+imm addressing.
__global__ __launch_bounds__(256, 2) void depthcnn_main(
    const _Float16* __restrict__ T, const float* __restrict__ gbuf,
    const float* __restrict__ bias, const _Float16* __restrict__ aprep,
    float* __restrict__ out)
{
    __shared__ __align__(1024) char sIn[4 * ROWBYTES];   // 66,560 B: 4 full T rows
    __shared__ _Float16 sWf[2][9][128];                  // 4,608 B -> 71,168 total

    const int blk    = blockIdx.x;
    const int b      = blk & 7;            // XCD-pinned: batch b -> XCD b
    const int strip  = blk >> 3;           // 2-row strip (0..63)
    const int ystart = strip << 1;

    const int tid  = threadIdx.x;
    const int wave = tid >> 6;             // px quarter 0..3
    const int lane = tid & 63;
    const int l15  = lane & 15;
    const int g4   = lane >> 4;
    const int x0w  = wave << 5;            // wave's 32-px base

    // ---- stage 4 full T rows (ystart..ystart+3) via async DMA (4160 chunks)
    {
        const char* Tb = (const char*)T + ((size_t)b * TROW + ystart) * ROWBYTES;
        #pragma unroll
        for (int tt = 0; tt < 17; ++tt) {
            int t = tt * 256 + tid;
            if (t < 4 * 1040) {
                int tr = t / 1040, c = t - tr * 1040;
                __builtin_amdgcn_global_load_lds(
                    (const AS1 uint32_t*)(Tb + (size_t)tr * ROWBYTES + c * 16),
                    (AS3 uint32_t*)(sIn + tr * ROWBYTES + c * 16), 16, 0, 0);
            }
        }
    }

    // ---- weight tap-0 frags for all 8 o-tiles, issued before the barrier
    const char* ap = (const char*)aprep + lane * 16;     // + (ot*18 + s)*1024
    f16x8 af[2][8];
    #pragma unroll
    for (int ot = 0; ot < 8; ++ot)
        af[0][ot] = *(const f16x8*)(ap + (size_t)(ot * 18) * 1024);

    // ---- wf: one (row, px) item per thread — fully parallel
    {
        const int r = tid >> 7, px = tid & 127, y = ystart + r;
        const float* g = gbuf + ((size_t)b * 2 + 1) * (HH * WW);
        float dc = 2.f * (g[y * WW + px] - 0.5f);
        float e[9];
        float ssum = 0.f;
        #pragma unroll
        for (int k = 0; k < 9; ++k) {
            int yy = y + (k / 3) - 1;
            int xx = px + (k % 3) - 1;
            float dn = 0.f;
            if ((unsigned)yy < 128u && (unsigned)xx < 128u)
                dn = 2.f * (g[yy * WW + xx] - 0.5f);
            float df = dn - dc;
            float ek = __expf(-df * df);
            e[k] = ek;
            ssum += ek;
        }
        float sc = 9.f / ssum;
        #pragma unroll
        for (int k = 0; k < 9; ++k) sWf[r][k][px] = (_Float16)(e[k] * sc);
    }

    __syncthreads();   // ONE barrier: DMA stage + wf visible. K-loop barrier-free.

    // ---- precomputed swizzled LDS bases: 6 input (dx,ch) + 1 wf
    const char* binA[3][2];
    #pragma unroll
    for (int d = 0; d < 3; ++d)
        #pragma unroll
        for (int ch = 0; ch < 2; ++ch)
            binA[d][ch] = sIn + (x0w << 7) + (((l15 + d) << 7)
                        + ((((ch << 2) | g4) ^ ((l15 + d) & 7)) << 4));
    const char* bwf = (const char*)&sWf[0][0][0] + ((x0w + l15) << 1);
    // imm: (r*9+k)*256 + pt*32

    f32x4 acc[2][2][8];   // [row][pt][ot] — 128 AGPRs
    #pragma unroll
    for (int r = 0; r < 2; ++r)
        #pragma unroll
        for (int pt = 0; pt < 2; ++pt)
            #pragma unroll
            for (int ot = 0; ot < 8; ++ot)
                acc[r][pt][ot] = (f32x4){0.f, 0.f, 0.f, 0.f};

    #pragma unroll
    for (int s = 0; s < 18; ++s) {
        if (s < 17) {   // prefetch next K-step's 8 weight frags (L2-hot, 8KB/wave)
            #pragma unroll
            for (int ot = 0; ot < 8; ++ot)
                af[(s + 1) & 1][ot] = *(const f16x8*)(ap + (size_t)(ot * 18 + s + 1) * 1024);
        }
        const int tap = s >> 1;
        const int ch  = s & 1;
        const int dy  = tap / 3;
        const int dx  = tap - 3 * dy;
        #pragma unroll
        for (int r = 0; r < 2; ++r) {
            _Float16 wh[2];
            #pragma unroll
            for (int pt = 0; pt < 2; ++pt)
                wh[pt] = *(const _Float16*)(bwf + ((r * 9 + tap) * 256 + pt * 32));
            f16x8 bf[2];
            #pragma unroll
            for (int pt = 0; pt < 2; ++pt) {
                f16x8 iv = *(const f16x8*)(binA[dx][ch]
                         + ((r + dy) * ROWBYTES + (pt << 11)));
                f16x8 w8 = {wh[pt], wh[pt], wh[pt], wh[pt],
                            wh[pt], wh[pt], wh[pt], wh[pt]};
                bf[pt] = iv * w8;
            }
            __builtin_amdgcn_s_setprio(1);
            #pragma unroll
            for (int ot = 0; ot < 8; ++ot) {
                acc[r][0][ot] = __builtin_amdgcn_mfma_f32_16x16x32_f16(
                    af[s & 1][ot], bf[0], acc[r][0][ot], 0, 0, 0);
                acc[r][1][ot] = __builtin_amdgcn_mfma_f32_16x16x32_f16(
                    af[s & 1][ot], bf[1], acc[r][1][ot], 0, 0, 0);
            }
            __builtin_amdgcn_s_setprio(0);
        }
    }

    // ---- epilogue: D row = o (g4*4+r4 within tile), col = px (l15) -> 64B lines
    float* ob = out + (size_t)b * COUT * (HH * WW);
    #pragma unroll
    for (int ot = 0; ot < 8; ++ot) {
        #pragma unroll
        for (int r4 = 0; r4 < 4; ++r4) {
            const int o = (ot << 4) + (g4 << 2) + r4;
            const float bv = bias[o];
            #pragma unroll
            for (int r = 0; r < 2; ++r) {
                #pragma unroll
                for (int pt = 0; pt < 2; ++pt) {
                    const int px = x0w + (pt << 4) + l15;
                    ob[(size_t)o * (HH * WW) + (size_t)(ystart + r) * WW + px]
                        = acc[r][pt][ot][r4] + bv;
                }
            }
        }
    }
}

extern "C" void kernel_launch(void* const* d_in, const int* in_sizes, int n_in,
                              void* d_out, int out_size, void* d_ws, size_t ws_size,
                              hipStream_t stream) {
    const float* inp  = (const float*)d_in[0];
    const float* gbuf = (const float*)d_in[1];
    const float* wts  = (const float*)d_in[2];
    const float* bias = (const float*)d_in[3];

    _Float16* T  = (_Float16*)d_ws;                     // 17,305,600 B
    _Float16* bp = (_Float16*)((char*)d_ws + TSIZE);    // +147,456 B

    hipLaunchKernelGGL(prep_plus, dim3(353), dim3(256), 0, stream, wts, bp, T);
    hipLaunchKernelGGL(transpose_pass, dim3(BB * HH), dim3(256), 0, stream, inp, T);
    hipLaunchKernelGGL(depthcnn_main, dim3(512), dim3(256), 0, stream,
                       T, gbuf, bias, bp, (float*)d_out);
}

// Round 16
// 47.543 us; speedup vs baseline: 1.7521x; 1.0015x over previous
//
#include <hip/hip_runtime.h>
#include <hip/hip_bf16.h>
#include <stdint.h>

typedef _Float16 f16x8 __attribute__((ext_vector_type(8)));
typedef float    f32x4 __attribute__((ext_vector_type(4)));

#define CIN   64
#define COUT  128
#define HH    128
#define WW    128
#define BB    8

#define TROW  130                         // y' rows per batch (halo rows 0,129 zero)
#define ROWBYTES (130 * 128)              // 16640 B per (b,y') row: 130 x' * 64c * 2B
#define TSIZE ((size_t)BB * TROW * ROWBYTES)   // 17,305,600 B

#define AS1 __attribute__((address_space(1)))
#define AS3 __attribute__((address_space(3)))

// T row byte layout (f16, c-innermost, XOR-swizzled 16B slots):
//   byte(x', c) = x'*128 + (((c>>3) ^ (x'&7)) << 4) + (c&7)*2

// ---------------- pass 0: weights -> MFMA-A frag order (f16) + halo-row zeroing --
// frag[((ot*18 + s)*64 + lane)*8 + j] = W2[ot*16+(l&15)][c*9+k],
//   c = (s&1)*32 + ((l>>4)&3)*8 + j; k = s>>1
__global__ void prep_plus(const float* __restrict__ wflat, _Float16* __restrict__ bp,
                          _Float16* __restrict__ T) {
    int gid = blockIdx.x * 256 + threadIdx.x;
    if (gid < 8 * 18 * 64 * 8) {
        int j = gid & 7;
        int l = (gid >> 3) & 63;
        int s = (gid >> 9) % 18;
        int n = gid / (18 * 512);
        int o = n * 16 + (l & 15);
        int c = ((s & 1) << 5) + ((l >> 4) << 3) + j;
        int k = s >> 1;
        bp[gid] = (_Float16)wflat[o * 576 + c * 9 + k];
        return;
    }
    int h = gid - 8 * 18 * 64 * 8;
    if (h < 16 * 1040) {                  // zero halo rows y'=0,129 of each batch
        int row = h / 1040, c = h - row * 1040;
        int b = row >> 1, yp = (row & 1) * 129;
        f16x8 z = {};
        *(f16x8*)((char*)T + (size_t)(b * TROW + yp) * ROWBYTES + c * 16) = z;
    }
}

// ---------------- pass 1: input (B,C,H,W) f32 -> T[b][y'][x'][c] f16, swizzled ---
__global__ __launch_bounds__(256) void transpose_pass(const float* __restrict__ inp,
                                                      _Float16* __restrict__ T) {
    __shared__ float sT[64][129];
    const int b   = blockIdx.x >> 7;
    const int y   = blockIdx.x & 127;
    const int tid = threadIdx.x;

    const float* ib = inp + ((long)b * CIN * HH + y) * WW;
    const int xq = tid & 31, c8 = tid >> 5;
    #pragma unroll
    for (int i = 0; i < 8; ++i) {
        int c = c8 * 8 + i;
        float4 v = *(const float4*)(ib + (long)c * (HH * WW) + (xq << 2));
        *(float4*)&sT[c][xq << 2] = v;
    }
    __syncthreads();

    const int x  = tid & 127;
    const int ch = tid >> 7;
    char* rowp = (char*)T + (size_t)(b * TROW + y + 1) * ROWBYTES + (size_t)(x + 1) * 128;
    const int sw = (x + 1) & 7;
    for (int c0 = ch * 8; c0 < 64; c0 += 16) {
        f16x8 v;
        #pragma unroll
        for (int j = 0; j < 8; ++j) v[j] = (_Float16)sT[c0 + j][x];
        *(f16x8*)(rowp + (((c0 >> 3) ^ sw) << 4)) = v;
    }
    if (tid < 16) {   // zero col halos x'=0, x'=129
        char* basep = (char*)T + (size_t)(b * TROW + y + 1) * ROWBYTES
                    + ((tid >> 3) ? 129 * 128 : 0) + (tid & 7) * 16;
        f16x8 z = {};
        *(f16x8*)basep = z;
    }
}

// ---- pass 2: main — block = (b, 2-row strip), FULL 128 px x 128 o ---------------
// 256 thr = 4 waves = 4 px-quarters; EACH wave computes ALL 128 o for its 32 px
// x 2 rows. Per K-step: 4 ds_read_b128 -> 32 MFMAs (read:MFMA = 0.125). Weights
// streamed once per wave (147KB, L2-hot) via 2-deep double buffer af[2][8].
// acc[2][2][8] in AGPRs. One barrier; K-loop barrier-free, base+imm addressing.
__global__ __launch_bounds__(256, 2) void depthcnn_main(
    const _Float16* __restrict__ T, const float* __restrict__ gbuf,
    const float* __restrict__ bias, const _Float16* __restrict__ aprep,
    float* __restrict__ out)
{
    __shared__ __align__(1024) char sIn[4 * ROWBYTES];   // 66,560 B: 4 full T rows
    __shared__ _Float16 sWf[2][9][128];                  // 4,608 B -> 71,168 total

    const int blk    = blockIdx.x;
    const int b      = blk & 7;            // XCD-pinned: batch b -> XCD b
    const int strip  = blk >> 3;           // 2-row strip (0..63)
    const int ystart = strip << 1;

    const int tid  = threadIdx.x;
    const int wave = tid >> 6;             // px quarter 0..3
    const int lane = tid & 63;
    const int l15  = lane & 15;
    const int g4   = lane >> 4;
    const int x0w  = wave << 5;            // wave's 32-px base

    // ---- stage 4 full T rows (ystart..ystart+3) via async DMA (4160 chunks)
    {
        const char* Tb = (const char*)T + ((size_t)b * TROW + ystart) * ROWBYTES;
        #pragma unroll
        for (int tt = 0; tt < 17; ++tt) {
            int t = tt * 256 + tid;
            if (t < 4 * 1040) {
                int tr = t / 1040, c = t - tr * 1040;
                __builtin_amdgcn_global_load_lds(
                    (const AS1 uint32_t*)(Tb + (size_t)tr * ROWBYTES + c * 16),
                    (AS3 uint32_t*)(sIn + tr * ROWBYTES + c * 16), 16, 0, 0);
            }
        }
    }

    // ---- weight tap-0 frags for all 8 o-tiles, issued before the barrier
    const char* ap = (const char*)aprep + lane * 16;     // + (ot*18 + s)*1024
    f16x8 af[2][8];
    #pragma unroll
    for (int ot = 0; ot < 8; ++ot)
        af[0][ot] = *(const f16x8*)(ap + (size_t)(ot * 18) * 1024);

    // ---- wf: one (row, px) item per thread — fully parallel
    {
        const int r = tid >> 7, px = tid & 127, y = ystart + r;
        const float* g = gbuf + ((size_t)b * 2 + 1) * (HH * WW);
        float dc = 2.f * (g[y * WW + px] - 0.5f);
        float e[9];
        float ssum = 0.f;
        #pragma unroll
        for (int k = 0; k < 9; ++k) {
            int yy = y + (k / 3) - 1;
            int xx = px + (k % 3) - 1;
            float dn = 0.f;
            if ((unsigned)yy < 128u && (unsigned)xx < 128u)
                dn = 2.f * (g[yy * WW + xx] - 0.5f);
            float df = dn - dc;
            float ek = __expf(-df * df);
            e[k] = ek;
            ssum += ek;
        }
        float sc = 9.f / ssum;
        #pragma unroll
        for (int k = 0; k < 9; ++k) sWf[r][k][px] = (_Float16)(e[k] * sc);
    }

    __syncthreads();   // ONE barrier: DMA stage + wf visible. K-loop barrier-free.

    // ---- precomputed swizzled LDS bases: 6 input (dx,ch) + 1 wf
    const char* binA[3][2];
    #pragma unroll
    for (int d = 0; d < 3; ++d)
        #pragma unroll
        for (int ch = 0; ch < 2; ++ch)
            binA[d][ch] = sIn + (x0w << 7) + (((l15 + d) << 7)
                        + ((((ch << 2) | g4) ^ ((l15 + d) & 7)) << 4));
    const char* bwf = (const char*)&sWf[0][0][0] + ((x0w + l15) << 1);
    // imm: (r*9+k)*256 + pt*32

    f32x4 acc[2][2][8];   // [row][pt][ot] — 128 AGPRs
    #pragma unroll
    for (int r = 0; r < 2; ++r)
        #pragma unroll
        for (int pt = 0; pt < 2; ++pt)
            #pragma unroll
            for (int ot = 0; ot < 8; ++ot)
                acc[r][pt][ot] = (f32x4){0.f, 0.f, 0.f, 0.f};

    #pragma unroll
    for (int s = 0; s < 18; ++s) {
        if (s < 17) {   // prefetch next K-step's 8 weight frags (L2-hot, 8KB/wave)
            #pragma unroll
            for (int ot = 0; ot < 8; ++ot)
                af[(s + 1) & 1][ot] = *(const f16x8*)(ap + (size_t)(ot * 18 + s + 1) * 1024);
        }
        const int tap = s >> 1;
        const int ch  = s & 1;
        const int dy  = tap / 3;
        const int dx  = tap - 3 * dy;
        #pragma unroll
        for (int r = 0; r < 2; ++r) {
            _Float16 wh[2];
            #pragma unroll
            for (int pt = 0; pt < 2; ++pt)
                wh[pt] = *(const _Float16*)(bwf + ((r * 9 + tap) * 256 + pt * 32));
            f16x8 bf[2];
            #pragma unroll
            for (int pt = 0; pt < 2; ++pt) {
                f16x8 iv = *(const f16x8*)(binA[dx][ch]
                         + ((r + dy) * ROWBYTES + (pt << 11)));
                f16x8 w8 = {wh[pt], wh[pt], wh[pt], wh[pt],
                            wh[pt], wh[pt], wh[pt], wh[pt]};
                bf[pt] = iv * w8;
            }
            __builtin_amdgcn_s_setprio(1);
            #pragma unroll
            for (int ot = 0; ot < 8; ++ot) {
                acc[r][0][ot] = __builtin_amdgcn_mfma_f32_16x16x32_f16(
                    af[s & 1][ot], bf[0], acc[r][0][ot], 0, 0, 0);
                acc[r][1][ot] = __builtin_amdgcn_mfma_f32_16x16x32_f16(
                    af[s & 1][ot], bf[1], acc[r][1][ot], 0, 0, 0);
            }
            __builtin_amdgcn_s_setprio(0);
        }
    }

    // ---- epilogue: D row = o (g4*4+r4 within tile), col = px (l15) -> 64B lines
    float* ob = out + (size_t)b * COUT * (HH * WW);
    #pragma unroll
    for (int ot = 0; ot < 8; ++ot) {
        #pragma unroll
        for (int r4 = 0; r4 < 4; ++r4) {
            const int o = (ot << 4) + (g4 << 2) + r4;
            const float bv = bias[o];
            #pragma unroll
            for (int r = 0; r < 2; ++r) {
                #pragma unroll
                for (int pt = 0; pt < 2; ++pt) {
                    const int px = x0w + (pt << 4) + l15;
                    ob[(size_t)o * (HH * WW) + (size_t)(ystart + r) * WW + px]
                        = acc[r][pt][ot][r4] + bv;
                }
            }
        }
    }
}

extern "C" void kernel_launch(void* const* d_in, const int* in_sizes, int n_in,
                              void* d_out, int out_size, void* d_ws, size_t ws_size,
                              hipStream_t stream) {
    const float* inp  = (const float*)d_in[0];
    const float* gbuf = (const float*)d_in[1];
    const float* wts  = (const float*)d_in[2];
    const float* bias = (const float*)d_in[3];

    _Float16* T  = (_Float16*)d_ws;                     // 17,305,600 B
    _Float16* bp = (_Float16*)((char*)d_ws + TSIZE);    // +147,456 B

    hipLaunchKernelGGL(prep_plus, dim3(353), dim3(256), 0, stream, wts, bp, T);
    hipLaunchKernelGGL(transpose_pass, dim3(BB * HH), dim3(256), 0, stream, inp, T);
    hipLaunchKernelGGL(depthcnn_main, dim3(512), dim3(256), 0, stream,
                       T, gbuf, bias, bp, (float*)d_out);
}